// Round 5
// baseline (1632.469 us; speedup 1.0000x reference)
//
#include <hip/hip_runtime.h>

#define NN 100000
#define NE 1600000
#define NA (NE + NN)          // augmented edges = E + N self loops
#define DD 64
#define HH 2
#define CC 64
#define HC 128
#define EDIM 16
#define NG 64

// ---- workspace layout (in floats) ----
static const long OFF_CNT = 0;                       // [G]
static const long OFF_SUM = 64;                      // [G*D]
static const long OFF_VAR = OFF_SUM + 64 * 64;       // [G*D]
static const long OFF_A   = OFF_VAR + 64 * 64;       // [G*D]  scale
static const long OFF_B   = OFF_A + 64 * 64;         // [G*D]  shift
static const long OFF_DEG = OFF_B + 64 * 64;         // [N]
static const long OFF_LA  = OFF_DEG + NN;            // [N*ED] loop_attr sums
static const long OFF_MK  = OFF_LA + (long)NN * EDIM;   // [N*H] max keys (uint)
static const long OFF_DEN = OFF_MK + (long)NN * HH;     // [N*H]
static const long ZEND    = OFF_DEN + (long)NN * HH;    // zero [0, ZEND)
static const long OFF_LOG = ZEND;                       // [NA*H] logit -> ev
static const long OFF_XL  = OFF_LOG + (long)NA * HH;    // [N*HC] layout [n][c][h]
static const long OFF_XR  = OFF_XL + (long)NN * HC;     // [N*HC] layout [n][c][h]

// ordered-key encoding for float atomic max (init key 0 == -inf sentinel)
__device__ __forceinline__ unsigned fkey(float f) {
    unsigned b = __float_as_uint(f);
    return (b & 0x80000000u) ? ~b : (b | 0x80000000u);
}
__device__ __forceinline__ float funkey(unsigned k) {
    unsigned b = (k & 0x80000000u) ? (k & 0x7fffffffu) : ~k;
    return __uint_as_float(b);
}

// K0: zero accumulators, init out with bias
__global__ void k_init(float* __restrict__ ws, float* __restrict__ out,
                       const float* __restrict__ bias) {
    long stride = (long)gridDim.x * blockDim.x;
    long i0 = (long)blockIdx.x * blockDim.x + threadIdx.x;
    for (long i = i0; i < ZEND; i += stride) ws[i] = 0.f;
    for (long i = i0; i < (long)NN * CC; i += stride) out[i] = bias[i & 63];
}

// K1: per-graph sum + count (batch is sorted -> few atomic flushes)
__global__ void k_gn_sum(const float* __restrict__ x, const int* __restrict__ batch,
                         float* __restrict__ sumx, float* __restrict__ cnt) {
    const int d = threadIdx.x;  // 64 threads
    int n0 = blockIdx.x * 128;
    if (n0 >= NN) return;
    int n1 = min(n0 + 128, NN);
    int curg = batch[n0];
    float acc = 0.f, cacc = 0.f;
    for (int n = n0; n < n1; ++n) {
        int g = batch[n];
        if (g != curg) {
            atomicAdd(&sumx[curg * DD + d], acc);
            if (d == 0) atomicAdd(&cnt[curg], cacc);
            curg = g; acc = 0.f; cacc = 0.f;
        }
        acc += x[(long)n * DD + d];
        cacc += 1.f;
    }
    atomicAdd(&sumx[curg * DD + d], acc);
    if (d == 0) atomicAdd(&cnt[curg], cacc);
}

// K2: per-graph variance of xc = x - ms*mean
__global__ void k_gn_var(const float* __restrict__ x, const int* __restrict__ batch,
                         const float* __restrict__ sumx, const float* __restrict__ cnt,
                         const float* __restrict__ ms, float* __restrict__ varx) {
    const int d = threadIdx.x;
    int n0 = blockIdx.x * 128;
    if (n0 >= NN) return;
    int n1 = min(n0 + 128, NN);
    float msd = ms[d];
    int curg = batch[n0];
    float cg = fmaxf(cnt[curg], 1.f);
    float mu = msd * (sumx[curg * DD + d] / cg);
    float acc = 0.f;
    for (int n = n0; n < n1; ++n) {
        int g = batch[n];
        if (g != curg) {
            atomicAdd(&varx[curg * DD + d], acc);
            curg = g; acc = 0.f;
            cg = fmaxf(cnt[curg], 1.f);
            mu = msd * (sumx[curg * DD + d] / cg);
        }
        float xc = x[(long)n * DD + d] - mu;
        acc += xc * xc;
    }
    atomicAdd(&varx[curg * DD + d], acc);
}

// K2b: fold norm into per-(g,d) affine h = x*A + B
__global__ void k_gn_ab(const float* __restrict__ sumx, const float* __restrict__ varx,
                        const float* __restrict__ cnt, const float* __restrict__ w,
                        const float* __restrict__ b, const float* __restrict__ ms,
                        float* __restrict__ A, float* __restrict__ B) {
    int i = blockIdx.x * 256 + threadIdx.x;
    if (i >= NG * DD) return;
    int g = i >> 6, d = i & 63;
    float cg = fmaxf(cnt[g], 1.f);
    float mu = ms[d] * (sumx[i] / cg);
    float a = w[d] * rsqrtf(varx[i] / cg + 1e-5f);
    A[i] = a;
    B[i] = b[d] - mu * a;
}

// K3: h = relu(x*A+B); xl = h@Wl + bl ; xr = h@Wr + br
// stored interleaved: xl[n*128 + c*2 + h_head]
__global__ __launch_bounds__(128) void k_gemm(
    const float* __restrict__ x, const int* __restrict__ batch,
    const float* __restrict__ A, const float* __restrict__ B,
    const float* __restrict__ Wl, const float* __restrict__ bl,
    const float* __restrict__ Wr, const float* __restrict__ br,
    float* __restrict__ xl, float* __restrict__ xr) {
    __shared__ float hs[16 * 64];
    const int t = threadIdx.x;  // 128: col j = t (for both Wl and Wr)
    float wlr[64], wrr[64];
#pragma unroll
    for (int d = 0; d < 64; ++d) {
        wlr[d] = Wl[d * HC + t];
        wrr[d] = Wr[d * HC + t];
    }
    float blv = bl[t], brv = br[t];
    const long n0 = (long)blockIdx.x * 16;
    // phase 1: normalized+relu tile into LDS
    for (int e = t; e < 16 * 64; e += 128) {
        int i = e >> 6, d = e & 63;
        int g = batch[n0 + i];
        float hv = x[n0 * 64 + e] * A[g * 64 + d] + B[g * 64 + d];
        hs[e] = fmaxf(hv, 0.f);
    }
    __syncthreads();
    const float4* h4 = (const float4*)hs;
    const long co = (long)(t & 63) * 2 + (t >> 6);  // interleaved column offset
    for (int i = 0; i < 16; ++i) {
        float al = blv, ar = brv;
#pragma unroll
        for (int q = 0; q < 16; ++q) {
            float4 hv = h4[i * 16 + q];
            al += hv.x * wlr[q * 4 + 0] + hv.y * wlr[q * 4 + 1] +
                  hv.z * wlr[q * 4 + 2] + hv.w * wlr[q * 4 + 3];
            ar += hv.x * wrr[q * 4 + 0] + hv.y * wrr[q * 4 + 1] +
                  hv.z * wrr[q * 4 + 2] + hv.w * wrr[q * 4 + 3];
        }
        xl[(n0 + i) * HC + co] = al;
        xr[(n0 + i) * HC + co] = ar;
    }
}

// K4: deg + loop_attr sums (scatter by dst)
__global__ void k_loopattr(const int* __restrict__ ei, const float* __restrict__ eattr,
                           float* __restrict__ deg, float* __restrict__ la) {
    long tid = (long)blockIdx.x * 256 + threadIdx.x;
    long stride = (long)gridDim.x * 256;
    for (long i = tid; i < (long)NE * EDIM; i += stride) {
        long e = i >> 4;
        int k = (int)(i & 15);
        int d = ei[NE + e];
        atomicAdd(&la[(long)d * EDIM + k], eattr[i]);
        if (k == 0) atomicAdd(&deg[d], 1.f);
    }
}

// K5: per augmented edge: ee = ea@We; logit = <leakyrelu(xl[s]+xr[d]+ee), att>; atomicMax m
__global__ __launch_bounds__(256) void k_logits(
    const int* __restrict__ ei, const float* __restrict__ eattr,
    const float* __restrict__ We, const float* __restrict__ att,
    const float* __restrict__ deg, const float* __restrict__ la,
    const float* __restrict__ xl, const float* __restrict__ xr,
    float* __restrict__ logit, unsigned* __restrict__ mkey) {
    __shared__ float we_s[EDIM * HC];
    for (int i = threadIdx.x; i < EDIM * HC; i += 256) we_s[i] = We[i];
    __syncthreads();
    const int lane = threadIdx.x & 63;
    const int wid = threadIdx.x >> 6;
    const float a0 = att[lane], a1 = att[64 + lane];
    long wgid = (long)blockIdx.x * 4 + wid;
    long nw = (long)gridDim.x * 4;
    for (long e = wgid; e < NA; e += nw) {
        int s, d2;
        float eav;
        if (e < NE) {
            s = ei[e]; d2 = ei[NE + e];
            eav = eattr[e * EDIM + (lane & 15)];
        } else {
            int n = (int)(e - NE); s = n; d2 = n;
            eav = la[(long)n * EDIM + (lane & 15)] / fmaxf(deg[n], 1.f);
        }
        float ee0 = 0.f, ee1 = 0.f;
#pragma unroll
        for (int k = 0; k < 16; ++k) {
            float ak = __shfl(eav, k);
            ee0 += ak * we_s[k * HC + lane];
            ee1 += ak * we_s[k * HC + 64 + lane];
        }
        float2 xlv = *(const float2*)&xl[(long)s * HC + lane * 2];
        float2 xrv = *(const float2*)&xr[(long)d2 * HC + lane * 2];
        float e0 = xlv.x + xrv.x + ee0;
        float e1 = xlv.y + xrv.y + ee1;
        float s0 = e0 > 0.f ? e0 : 0.2f * e0;
        float s1 = e1 > 0.f ? e1 : 0.2f * e1;
        float p0 = s0 * a0, p1 = s1 * a1;
#pragma unroll
        for (int off = 32; off > 0; off >>= 1) {
            p0 += __shfl_xor(p0, off);
            p1 += __shfl_xor(p1, off);
        }
        if (lane == 0) {
            logit[e * 2 + 0] = p0;
            logit[e * 2 + 1] = p1;
            atomicMax(&mkey[d2 * 2 + 0], fkey(p0));
            atomicMax(&mkey[d2 * 2 + 1], fkey(p1));
        }
    }
}

// K6: ev = exp(logit - m[dst]); denom += ev; overwrite logit buffer with ev
__global__ void k_denom(const int* __restrict__ ei, const unsigned* __restrict__ mkey,
                        float* __restrict__ logit, float* __restrict__ denom) {
    long i0 = (long)blockIdx.x * 256 + threadIdx.x;
    long stride = (long)gridDim.x * 256;
    for (long e = i0; e < NA; e += stride) {
        int d2 = (e < NE) ? ei[NE + e] : (int)(e - NE);
        float m0 = funkey(mkey[d2 * 2 + 0]);
        float m1 = funkey(mkey[d2 * 2 + 1]);
        float ev0 = __expf(logit[e * 2 + 0] - m0);
        float ev1 = __expf(logit[e * 2 + 1] - m1);
        logit[e * 2 + 0] = ev0;
        logit[e * 2 + 1] = ev1;
        atomicAdd(&denom[d2 * 2 + 0], ev0);
        atomicAdd(&denom[d2 * 2 + 1], ev1);
    }
}

// K7: out[dst] += 0.5 * sum_h alpha_h * xl[src,h,:]
__global__ __launch_bounds__(256) void k_scatter(
    const int* __restrict__ ei, const float* __restrict__ ev,
    const float* __restrict__ denom, const float* __restrict__ xl,
    float* __restrict__ out) {
    const int lane = threadIdx.x & 63;
    const int wid = threadIdx.x >> 6;
    long wgid = (long)blockIdx.x * 4 + wid;
    long nw = (long)gridDim.x * 4;
    for (long e = wgid; e < NA; e += nw) {
        int s, d2;
        if (e < NE) { s = ei[e]; d2 = ei[NE + e]; }
        else { int n = (int)(e - NE); s = n; d2 = n; }
        float2 evv = *(const float2*)&ev[e * 2];
        float al0 = evv.x / (denom[d2 * 2 + 0] + 1e-16f);
        float al1 = evv.y / (denom[d2 * 2 + 1] + 1e-16f);
        float2 xlv = *(const float2*)&xl[(long)s * HC + lane * 2];
        atomicAdd(&out[(long)d2 * CC + lane], 0.5f * (al0 * xlv.x + al1 * xlv.y));
    }
}

extern "C" void kernel_launch(void* const* d_in, const int* in_sizes, int n_in,
                              void* d_out, int out_size, void* d_ws, size_t ws_size,
                              hipStream_t stream) {
    const float* x    = (const float*)d_in[0];
    const float* eatt = (const float*)d_in[1];
    const float* gw   = (const float*)d_in[2];
    const float* gb   = (const float*)d_in[3];
    const float* gms  = (const float*)d_in[4];
    const float* Wl   = (const float*)d_in[5];
    const float* bl   = (const float*)d_in[6];
    const float* Wr   = (const float*)d_in[7];
    const float* br   = (const float*)d_in[8];
    const float* We   = (const float*)d_in[9];
    const float* att  = (const float*)d_in[10];
    const float* bias = (const float*)d_in[11];
    const int*   ei   = (const int*)d_in[12];
    const int*   batch= (const int*)d_in[13];
    float* out = (float*)d_out;
    float* ws = (float*)d_ws;

    float* cnt  = ws + OFF_CNT;
    float* sumx = ws + OFF_SUM;
    float* varx = ws + OFF_VAR;
    float* A    = ws + OFF_A;
    float* B    = ws + OFF_B;
    float* deg  = ws + OFF_DEG;
    float* la   = ws + OFF_LA;
    unsigned* mkey = (unsigned*)(ws + OFF_MK);
    float* den  = ws + OFF_DEN;
    float* logit= ws + OFF_LOG;
    float* xl   = ws + OFF_XL;
    float* xr   = ws + OFF_XR;

    hipLaunchKernelGGL(k_init, dim3(2048), dim3(256), 0, stream, ws, out, bias);
    hipLaunchKernelGGL(k_gn_sum, dim3((NN + 127) / 128), dim3(64), 0, stream,
                       x, batch, sumx, cnt);
    hipLaunchKernelGGL(k_gn_var, dim3((NN + 127) / 128), dim3(64), 0, stream,
                       x, batch, sumx, cnt, gms, varx);
    hipLaunchKernelGGL(k_gn_ab, dim3(16), dim3(256), 0, stream,
                       sumx, varx, cnt, gw, gb, gms, A, B);
    hipLaunchKernelGGL(k_gemm, dim3(NN / 16), dim3(128), 0, stream,
                       x, batch, A, B, Wl, bl, Wr, br, xl, xr);
    hipLaunchKernelGGL(k_loopattr, dim3(4096), dim3(256), 0, stream, ei, eatt, deg, la);
    hipLaunchKernelGGL(k_logits, dim3(4096), dim3(256), 0, stream,
                       ei, eatt, We, att, deg, la, xl, xr, logit, mkey);
    hipLaunchKernelGGL(k_denom, dim3(4096), dim3(256), 0, stream, ei, mkey, logit, den);
    hipLaunchKernelGGL(k_scatter, dim3(4096), dim3(256), 0, stream,
                       ei, logit, den, xl, out);
}

// Round 6
// 1602.428 us; speedup vs baseline: 1.0187x; 1.0187x over previous
//
#include <hip/hip_runtime.h>
#include <hip/hip_fp16.h>

#define NN 100000
#define NE 1600000
#define NA (NE + NN)          // augmented edges = E + N self loops
#define DD 64
#define HH 2
#define CC 64
#define HC 128
#define EDIM 16
#define NG 64

// ---- workspace layout (in floats) ----
static const long OFF_CNT = 0;                       // [G]
static const long OFF_SUM = 64;                      // [G*D]
static const long OFF_VAR = OFF_SUM + 64 * 64;       // [G*D]
static const long OFF_A   = OFF_VAR + 64 * 64;       // [G*D]  scale
static const long OFF_B   = OFF_A + 64 * 64;         // [G*D]  shift
static const long OFF_DEG = OFF_B + 64 * 64;         // [N]
static const long OFF_LA  = OFF_DEG + NN;            // [N*ED] loop_attr sums
static const long OFF_DEN = OFF_LA + (long)NN * EDIM;   // [N*H]
static const long ZEND    = OFF_DEN + (long)NN * HH;    // zero [0, ZEND)
static const long OFF_LOG = ZEND;                       // [NA*H] logit -> ev
static const long OFF_XL  = OFF_LOG + (long)NA * HH;    // halfs [N][C][H] = N*HC/2 floats
static const long OFF_XR  = OFF_XL + (long)NN * HC / 2;

// K0: zero accumulators, init out with bias
__global__ void k_init(float* __restrict__ ws, float* __restrict__ out,
                       const float* __restrict__ bias) {
    long stride = (long)gridDim.x * blockDim.x;
    long i0 = (long)blockIdx.x * blockDim.x + threadIdx.x;
    for (long i = i0; i < ZEND; i += stride) ws[i] = 0.f;
    for (long i = i0; i < (long)NN * CC; i += stride) out[i] = bias[i & 63];
}

// K1: per-graph sum + count (batch is sorted -> few atomic flushes)
__global__ void k_gn_sum(const float* __restrict__ x, const int* __restrict__ batch,
                         float* __restrict__ sumx, float* __restrict__ cnt) {
    const int d = threadIdx.x;  // 64 threads
    int n0 = blockIdx.x * 128;
    if (n0 >= NN) return;
    int n1 = min(n0 + 128, NN);
    int curg = batch[n0];
    float acc = 0.f, cacc = 0.f;
    for (int n = n0; n < n1; ++n) {
        int g = batch[n];
        if (g != curg) {
            atomicAdd(&sumx[curg * DD + d], acc);
            if (d == 0) atomicAdd(&cnt[curg], cacc);
            curg = g; acc = 0.f; cacc = 0.f;
        }
        acc += x[(long)n * DD + d];
        cacc += 1.f;
    }
    atomicAdd(&sumx[curg * DD + d], acc);
    if (d == 0) atomicAdd(&cnt[curg], cacc);
}

// K2: per-graph variance of xc = x - ms*mean
__global__ void k_gn_var(const float* __restrict__ x, const int* __restrict__ batch,
                         const float* __restrict__ sumx, const float* __restrict__ cnt,
                         const float* __restrict__ ms, float* __restrict__ varx) {
    const int d = threadIdx.x;
    int n0 = blockIdx.x * 128;
    if (n0 >= NN) return;
    int n1 = min(n0 + 128, NN);
    float msd = ms[d];
    int curg = batch[n0];
    float cg = fmaxf(cnt[curg], 1.f);
    float mu = msd * (sumx[curg * DD + d] / cg);
    float acc = 0.f;
    for (int n = n0; n < n1; ++n) {
        int g = batch[n];
        if (g != curg) {
            atomicAdd(&varx[curg * DD + d], acc);
            curg = g; acc = 0.f;
            cg = fmaxf(cnt[curg], 1.f);
            mu = msd * (sumx[curg * DD + d] / cg);
        }
        float xc = x[(long)n * DD + d] - mu;
        acc += xc * xc;
    }
    atomicAdd(&varx[curg * DD + d], acc);
}

// K2b: fold norm into per-(g,d) affine h = x*A + B
__global__ void k_gn_ab(const float* __restrict__ sumx, const float* __restrict__ varx,
                        const float* __restrict__ cnt, const float* __restrict__ w,
                        const float* __restrict__ b, const float* __restrict__ ms,
                        float* __restrict__ A, float* __restrict__ B) {
    int i = blockIdx.x * 256 + threadIdx.x;
    if (i >= NG * DD) return;
    int g = i >> 6, d = i & 63;
    float cg = fmaxf(cnt[g], 1.f);
    float mu = ms[d] * (sumx[i] / cg);
    float a = w[d] * rsqrtf(varx[i] / cg + 1e-5f);
    A[i] = a;
    B[i] = b[d] - mu * a;
}

// K3: h = relu(x*A+B); xl = h@Wl + bl ; xr = h@Wr + br  (fp16 out, [n][c][h] interleave)
__global__ __launch_bounds__(128) void k_gemm(
    const float* __restrict__ x, const int* __restrict__ batch,
    const float* __restrict__ A, const float* __restrict__ B,
    const float* __restrict__ Wl, const float* __restrict__ bl,
    const float* __restrict__ Wr, const float* __restrict__ br,
    __half* __restrict__ xl, __half* __restrict__ xr) {
    __shared__ float hs[16 * 64];
    const int t = threadIdx.x;  // 128: col j = t (for both Wl and Wr)
    float wlr[64], wrr[64];
#pragma unroll
    for (int d = 0; d < 64; ++d) {
        wlr[d] = Wl[d * HC + t];
        wrr[d] = Wr[d * HC + t];
    }
    float blv = bl[t], brv = br[t];
    const long n0 = (long)blockIdx.x * 16;
    for (int e = t; e < 16 * 64; e += 128) {
        int i = e >> 6, d = e & 63;
        int g = batch[n0 + i];
        float hv = x[n0 * 64 + e] * A[g * 64 + d] + B[g * 64 + d];
        hs[e] = fmaxf(hv, 0.f);
    }
    __syncthreads();
    const float4* h4 = (const float4*)hs;
    const long co = (long)(t & 63) * 2 + (t >> 6);  // interleaved column offset
    for (int i = 0; i < 16; ++i) {
        float al = blv, ar = brv;
#pragma unroll
        for (int q = 0; q < 16; ++q) {
            float4 hv = h4[i * 16 + q];
            al += hv.x * wlr[q * 4 + 0] + hv.y * wlr[q * 4 + 1] +
                  hv.z * wlr[q * 4 + 2] + hv.w * wlr[q * 4 + 3];
            ar += hv.x * wrr[q * 4 + 0] + hv.y * wrr[q * 4 + 1] +
                  hv.z * wrr[q * 4 + 2] + hv.w * wrr[q * 4 + 3];
        }
        xl[(n0 + i) * HC + co] = __float2half_rn(al);
        xr[(n0 + i) * HC + co] = __float2half_rn(ar);
    }
}

// K4: deg + loop_attr sums (scatter by dst)
__global__ void k_loopattr(const int* __restrict__ ei, const float* __restrict__ eattr,
                           float* __restrict__ deg, float* __restrict__ la) {
    long tid = (long)blockIdx.x * 256 + threadIdx.x;
    long stride = (long)gridDim.x * 256;
    for (long i = tid; i < (long)NE * EDIM; i += stride) {
        long e = i >> 4;
        int k = (int)(i & 15);
        int d = ei[NE + e];
        atomicAdd(&la[(long)d * EDIM + k], eattr[i]);
        if (k == 0) atomicAdd(&deg[d], 1.f);
    }
}

// K5: per augmented edge pair: ee = ea@We; logit = <leakyrelu(xl[s]+xr[d]+ee), att>
// no max-subtraction (|logit| <~ 2, exp safe). 2 edges per wave iteration for ILP.
__global__ __launch_bounds__(256) void k_logits(
    const int* __restrict__ ei, const float* __restrict__ eattr,
    const float* __restrict__ We, const float* __restrict__ att,
    const float* __restrict__ deg, const float* __restrict__ la,
    const __half2* __restrict__ xl2, const __half2* __restrict__ xr2,
    float2* __restrict__ logit) {
    __shared__ float we_s[EDIM * HC];
    for (int i = threadIdx.x; i < EDIM * HC; i += 256) we_s[i] = We[i];
    __syncthreads();
    const int lane = threadIdx.x & 63;
    const int wid = threadIdx.x >> 6;
    const float a0 = att[lane], a1 = att[64 + lane];
    long w = (long)blockIdx.x * 4 + wid;
    long nw = (long)gridDim.x * 4;
    const long NP = NA / 2;  // NA even
    for (long p = w; p < NP; p += nw) {
        const long e0 = 2 * p, e1 = 2 * p + 1;
        int s0, d0, s1, d1;
        float ea0, ea1;
        if (e0 < NE) {  // pair is wave-uniformly real or self (NE even)
            s0 = ei[e0]; d0 = ei[NE + e0];
            s1 = ei[e1]; d1 = ei[NE + e1];
            ea0 = eattr[e0 * EDIM + (lane & 15)];
            ea1 = eattr[e1 * EDIM + (lane & 15)];
        } else {
            int n0 = (int)(e0 - NE), n1 = (int)(e1 - NE);
            s0 = d0 = n0; s1 = d1 = n1;
            ea0 = la[(long)n0 * EDIM + (lane & 15)] / fmaxf(deg[n0], 1.f);
            ea1 = la[(long)n1 * EDIM + (lane & 15)] / fmaxf(deg[n1], 1.f);
        }
        // issue all 4 gathers up front
        float2 xl0 = __half22float2(xl2[(long)s0 * 64 + lane]);
        float2 xr0 = __half22float2(xr2[(long)d0 * 64 + lane]);
        float2 xl1 = __half22float2(xl2[(long)s1 * 64 + lane]);
        float2 xr1 = __half22float2(xr2[(long)d1 * 64 + lane]);
        float ee00 = 0.f, ee01 = 0.f, ee10 = 0.f, ee11 = 0.f;
#pragma unroll
        for (int k = 0; k < 16; ++k) {
            float ak0 = __shfl(ea0, k);
            float ak1 = __shfl(ea1, k);
            float w0 = we_s[k * HC + lane];
            float w1 = we_s[k * HC + 64 + lane];
            ee00 += ak0 * w0; ee01 += ak0 * w1;
            ee10 += ak1 * w0; ee11 += ak1 * w1;
        }
        float v00 = xl0.x + xr0.x + ee00;
        float v01 = xl0.y + xr0.y + ee01;
        float v10 = xl1.x + xr1.x + ee10;
        float v11 = xl1.y + xr1.y + ee11;
        v00 = v00 > 0.f ? v00 : 0.2f * v00;
        v01 = v01 > 0.f ? v01 : 0.2f * v01;
        v10 = v10 > 0.f ? v10 : 0.2f * v10;
        v11 = v11 > 0.f ? v11 : 0.2f * v11;
        float p00 = v00 * a0, p01 = v01 * a1;
        float p10 = v10 * a0, p11 = v11 * a1;
#pragma unroll
        for (int off = 32; off > 0; off >>= 1) {
            p00 += __shfl_xor(p00, off);
            p01 += __shfl_xor(p01, off);
            p10 += __shfl_xor(p10, off);
            p11 += __shfl_xor(p11, off);
        }
        if (lane == 0) logit[e0] = make_float2(p00, p01);
        if (lane == 1) logit[e1] = make_float2(p10, p11);
    }
}

// K6: ev = exp(logit); denom += ev; overwrite logit buffer with ev
__global__ void k_denom(const int* __restrict__ ei, float2* __restrict__ logit,
                        float* __restrict__ denom) {
    long i0 = (long)blockIdx.x * 256 + threadIdx.x;
    long stride = (long)gridDim.x * 256;
    for (long e = i0; e < NA; e += stride) {
        int d2 = (e < NE) ? ei[NE + e] : (int)(e - NE);
        float2 lv = logit[e];
        float ev0 = __expf(lv.x);
        float ev1 = __expf(lv.y);
        logit[e] = make_float2(ev0, ev1);
        atomicAdd(&denom[d2 * 2 + 0], ev0);
        atomicAdd(&denom[d2 * 2 + 1], ev1);
    }
}

// K7: out[dst] += 0.5 * sum_h alpha_h * xl[src,h,:]  (2 edges/iter ILP)
__global__ __launch_bounds__(256) void k_scatter(
    const int* __restrict__ ei, const float2* __restrict__ ev,
    const float2* __restrict__ denom, const __half2* __restrict__ xl2,
    float* __restrict__ out) {
    const int lane = threadIdx.x & 63;
    const int wid = threadIdx.x >> 6;
    long w = (long)blockIdx.x * 4 + wid;
    long nw = (long)gridDim.x * 4;
    const long NP = NA / 2;
    for (long p = w; p < NP; p += nw) {
        const long e0 = 2 * p, e1 = 2 * p + 1;
        int s0, d0, s1, d1;
        if (e0 < NE) {
            s0 = ei[e0]; d0 = ei[NE + e0];
            s1 = ei[e1]; d1 = ei[NE + e1];
        } else {
            s0 = d0 = (int)(e0 - NE);
            s1 = d1 = (int)(e1 - NE);
        }
        float2 ev0 = ev[e0], ev1 = ev[e1];
        float2 dn0 = denom[d0], dn1 = denom[d1];
        float2 x0 = __half22float2(xl2[(long)s0 * 64 + lane]);
        float2 x1 = __half22float2(xl2[(long)s1 * 64 + lane]);
        float al00 = ev0.x / (dn0.x + 1e-16f);
        float al01 = ev0.y / (dn0.y + 1e-16f);
        float al10 = ev1.x / (dn1.x + 1e-16f);
        float al11 = ev1.y / (dn1.y + 1e-16f);
        atomicAdd(&out[(long)d0 * CC + lane], 0.5f * (al00 * x0.x + al01 * x0.y));
        atomicAdd(&out[(long)d1 * CC + lane], 0.5f * (al10 * x1.x + al11 * x1.y));
    }
}

extern "C" void kernel_launch(void* const* d_in, const int* in_sizes, int n_in,
                              void* d_out, int out_size, void* d_ws, size_t ws_size,
                              hipStream_t stream) {
    const float* x    = (const float*)d_in[0];
    const float* eatt = (const float*)d_in[1];
    const float* gw   = (const float*)d_in[2];
    const float* gb   = (const float*)d_in[3];
    const float* gms  = (const float*)d_in[4];
    const float* Wl   = (const float*)d_in[5];
    const float* bl   = (const float*)d_in[6];
    const float* Wr   = (const float*)d_in[7];
    const float* br   = (const float*)d_in[8];
    const float* We   = (const float*)d_in[9];
    const float* att  = (const float*)d_in[10];
    const float* bias = (const float*)d_in[11];
    const int*   ei   = (const int*)d_in[12];
    const int*   batch= (const int*)d_in[13];
    float* out = (float*)d_out;
    float* ws = (float*)d_ws;

    float* cnt  = ws + OFF_CNT;
    float* sumx = ws + OFF_SUM;
    float* varx = ws + OFF_VAR;
    float* A    = ws + OFF_A;
    float* B    = ws + OFF_B;
    float* deg  = ws + OFF_DEG;
    float* la   = ws + OFF_LA;
    float* den  = ws + OFF_DEN;
    float* logit= ws + OFF_LOG;
    __half* xl  = (__half*)(ws + OFF_XL);
    __half* xr  = (__half*)(ws + OFF_XR);

    hipLaunchKernelGGL(k_init, dim3(2048), dim3(256), 0, stream, ws, out, bias);
    hipLaunchKernelGGL(k_gn_sum, dim3((NN + 127) / 128), dim3(64), 0, stream,
                       x, batch, sumx, cnt);
    hipLaunchKernelGGL(k_gn_var, dim3((NN + 127) / 128), dim3(64), 0, stream,
                       x, batch, sumx, cnt, gms, varx);
    hipLaunchKernelGGL(k_gn_ab, dim3(16), dim3(256), 0, stream,
                       sumx, varx, cnt, gw, gb, gms, A, B);
    hipLaunchKernelGGL(k_gemm, dim3(NN / 16), dim3(128), 0, stream,
                       x, batch, A, B, Wl, bl, Wr, br, xl, xr);
    hipLaunchKernelGGL(k_loopattr, dim3(4096), dim3(256), 0, stream, ei, eatt, deg, la);
    hipLaunchKernelGGL(k_logits, dim3(4096), dim3(256), 0, stream,
                       ei, eatt, We, att, deg, la,
                       (const __half2*)xl, (const __half2*)xr, (float2*)logit);
    hipLaunchKernelGGL(k_denom, dim3(4096), dim3(256), 0, stream,
                       ei, (float2*)logit, den);
    hipLaunchKernelGGL(k_scatter, dim3(4096), dim3(256), 0, stream,
                       ei, (const float2*)logit, (const float2*)den,
                       (const __half2*)xl, out);
}

// Round 7
// 1405.906 us; speedup vs baseline: 1.1612x; 1.1398x over previous
//
#include <hip/hip_runtime.h>
#include <hip/hip_fp16.h>

#define NN 100000
#define NE 1600000
#define NA (NE + NN)          // augmented edges = E + N self loops
#define DD 64
#define HH 2
#define CC 64
#define HC 128
#define EDIM 16
#define NG 64

// ---- workspace layout (in floats) ----
static const long OFF_CNT = 0;                       // [G]
static const long OFF_SUM = 64;                      // [G*D]
static const long OFF_SUM2= OFF_SUM + 64 * 64;       // [G*D]
static const long OFF_A   = OFF_SUM2 + 64 * 64;      // [G*D]  scale
static const long OFF_B   = OFF_A + 64 * 64;         // [G*D]  shift
static const long OFF_DEG = OFF_B + 64 * 64;         // [N]
static const long OFF_LA  = OFF_DEG + NN;            // [N*ED] loop_attr sums
static const long OFF_DEN = OFF_LA + (long)NN * EDIM;   // [N*H]
static const long ZEND    = OFF_DEN + (long)NN * HH;    // zero [0, ZEND)
static const long OFF_LOG = ZEND;                       // [NA*H] ev
static const long OFF_XL  = OFF_LOG + (long)NA * HH;    // halfs [N][C][H] = N*HC/2 floats
static const long OFF_XR  = OFF_XL + (long)NN * HC / 2;

// K0: zero accumulators, init out with bias
__global__ void k_init(float* __restrict__ ws, float* __restrict__ out,
                       const float* __restrict__ bias) {
    long stride = (long)gridDim.x * blockDim.x;
    long i0 = (long)blockIdx.x * blockDim.x + threadIdx.x;
    for (long i = i0; i < ZEND; i += stride) ws[i] = 0.f;
    for (long i = i0; i < (long)NN * CC; i += stride) out[i] = bias[i & 63];
}

// K1: per-graph sum + sum-of-squares + count in ONE pass (batch sorted)
__global__ void k_gn_sum(const float* __restrict__ x, const int* __restrict__ batch,
                         float* __restrict__ sumx, float* __restrict__ sum2,
                         float* __restrict__ cnt) {
    const int d = threadIdx.x;  // 64 threads
    int n0 = blockIdx.x * 16;
    if (n0 >= NN) return;
    int n1 = min(n0 + 16, NN);
    int curg = batch[n0];
    float a1 = 0.f, a2 = 0.f, ca = 0.f;
    for (int n = n0; n < n1; ++n) {
        int g = batch[n];
        if (g != curg) {
            atomicAdd(&sumx[curg * DD + d], a1);
            atomicAdd(&sum2[curg * DD + d], a2);
            if (d == 0) atomicAdd(&cnt[curg], ca);
            curg = g; a1 = 0.f; a2 = 0.f; ca = 0.f;
        }
        float v = x[(long)n * DD + d];
        a1 += v; a2 += v * v; ca += 1.f;
    }
    atomicAdd(&sumx[curg * DD + d], a1);
    atomicAdd(&sum2[curg * DD + d], a2);
    if (d == 0) atomicAdd(&cnt[curg], ca);
}

// K2b: fold norm into per-(g,d) affine h = x*A + B
// var = E[x^2] - 2*msm*mean + msm^2, msm = ms*mean
__global__ void k_gn_ab(const float* __restrict__ sumx, const float* __restrict__ sum2,
                        const float* __restrict__ cnt, const float* __restrict__ w,
                        const float* __restrict__ b, const float* __restrict__ ms,
                        float* __restrict__ A, float* __restrict__ B) {
    int i = blockIdx.x * 256 + threadIdx.x;
    if (i >= NG * DD) return;
    int g = i >> 6, d = i & 63;
    float cg = fmaxf(cnt[g], 1.f);
    float mean = sumx[i] / cg;
    float msm = ms[d] * mean;
    float var = fmaxf(sum2[i] / cg - 2.f * msm * mean + msm * msm, 0.f);
    float a = w[d] * rsqrtf(var + 1e-5f);
    A[i] = a;
    B[i] = b[d] - msm * a;
}

// K3: h = relu(x*A+B); xl = h@Wl + bl ; xr = h@Wr + br  (fp16 out, [n][c][h] interleave)
__global__ __launch_bounds__(128) void k_gemm(
    const float* __restrict__ x, const int* __restrict__ batch,
    const float* __restrict__ A, const float* __restrict__ B,
    const float* __restrict__ Wl, const float* __restrict__ bl,
    const float* __restrict__ Wr, const float* __restrict__ br,
    __half* __restrict__ xl, __half* __restrict__ xr) {
    __shared__ float hs[16 * 64];
    const int t = threadIdx.x;  // 128: col j = t (for both Wl and Wr)
    float wlr[64], wrr[64];
#pragma unroll
    for (int d = 0; d < 64; ++d) {
        wlr[d] = Wl[d * HC + t];
        wrr[d] = Wr[d * HC + t];
    }
    float blv = bl[t], brv = br[t];
    const long n0 = (long)blockIdx.x * 16;
    for (int e = t; e < 16 * 64; e += 128) {
        int i = e >> 6, d = e & 63;
        int g = batch[n0 + i];
        float hv = x[n0 * 64 + e] * A[g * 64 + d] + B[g * 64 + d];
        hs[e] = fmaxf(hv, 0.f);
    }
    __syncthreads();
    const float4* h4 = (const float4*)hs;
    const long co = (long)(t & 63) * 2 + (t >> 6);  // interleaved column offset
    for (int i = 0; i < 16; ++i) {
        float al = blv, ar = brv;
#pragma unroll
        for (int q = 0; q < 16; ++q) {
            float4 hv = h4[i * 16 + q];
            al += hv.x * wlr[q * 4 + 0] + hv.y * wlr[q * 4 + 1] +
                  hv.z * wlr[q * 4 + 2] + hv.w * wlr[q * 4 + 3];
            ar += hv.x * wrr[q * 4 + 0] + hv.y * wrr[q * 4 + 1] +
                  hv.z * wrr[q * 4 + 2] + hv.w * wrr[q * 4 + 3];
        }
        xl[(n0 + i) * HC + co] = __float2half_rn(al);
        xr[(n0 + i) * HC + co] = __float2half_rn(ar);
    }
}

// K4: deg + loop_attr sums (scatter by dst)
__global__ void k_loopattr(const int* __restrict__ ei, const float* __restrict__ eattr,
                           float* __restrict__ deg, float* __restrict__ la) {
    long tid = (long)blockIdx.x * 256 + threadIdx.x;
    long stride = (long)gridDim.x * 256;
    for (long i = tid; i < (long)NE * EDIM; i += stride) {
        long e = i >> 4;
        int k = (int)(i & 15);
        int d = ei[NE + e];
        atomicAdd(&la[(long)d * EDIM + k], eattr[i]);
        if (k == 0) atomicAdd(&deg[d], 1.f);
    }
}

// K5: per edge pair: ee = ea@We; logit = <lrelu(xl[s]+xr[d]+ee), att>;
// ev = exp(logit) stored; denom accumulated by atomics (fused, no max pass).
__global__ __launch_bounds__(256) void k_logits(
    const int* __restrict__ ei, const float* __restrict__ eattr,
    const float* __restrict__ We, const float* __restrict__ att,
    const float* __restrict__ deg, const float* __restrict__ la,
    const __half2* __restrict__ xl2, const __half2* __restrict__ xr2,
    float2* __restrict__ evout, float* __restrict__ denom) {
    __shared__ float we_s[EDIM * HC];
    for (int i = threadIdx.x; i < EDIM * HC; i += 256) we_s[i] = We[i];
    __syncthreads();
    const int lane = threadIdx.x & 63;
    const int wid = threadIdx.x >> 6;
    const float a0 = att[lane], a1 = att[64 + lane];
    long w = (long)blockIdx.x * 4 + wid;
    long nw = (long)gridDim.x * 4;
    const long NP = NA / 2;  // NA even
    for (long p = w; p < NP; p += nw) {
        const long e0 = 2 * p, e1 = 2 * p + 1;
        int s0, d0, s1, d1;
        float ea0, ea1;
        if (e0 < NE) {  // pair is wave-uniformly real or self (NE even)
            s0 = ei[e0]; d0 = ei[NE + e0];
            s1 = ei[e1]; d1 = ei[NE + e1];
            ea0 = eattr[e0 * EDIM + (lane & 15)];
            ea1 = eattr[e1 * EDIM + (lane & 15)];
        } else {
            int n0 = (int)(e0 - NE), n1 = (int)(e1 - NE);
            s0 = d0 = n0; s1 = d1 = n1;
            ea0 = la[(long)n0 * EDIM + (lane & 15)] / fmaxf(deg[n0], 1.f);
            ea1 = la[(long)n1 * EDIM + (lane & 15)] / fmaxf(deg[n1], 1.f);
        }
        // issue all 4 gathers up front
        float2 xl0 = __half22float2(xl2[(long)s0 * 64 + lane]);
        float2 xr0 = __half22float2(xr2[(long)d0 * 64 + lane]);
        float2 xl1 = __half22float2(xl2[(long)s1 * 64 + lane]);
        float2 xr1 = __half22float2(xr2[(long)d1 * 64 + lane]);
        float ee00 = 0.f, ee01 = 0.f, ee10 = 0.f, ee11 = 0.f;
#pragma unroll
        for (int k = 0; k < 16; ++k) {
            float ak0 = __shfl(ea0, k);
            float ak1 = __shfl(ea1, k);
            float w0 = we_s[k * HC + lane];
            float w1 = we_s[k * HC + 64 + lane];
            ee00 += ak0 * w0; ee01 += ak0 * w1;
            ee10 += ak1 * w0; ee11 += ak1 * w1;
        }
        float v00 = xl0.x + xr0.x + ee00;
        float v01 = xl0.y + xr0.y + ee01;
        float v10 = xl1.x + xr1.x + ee10;
        float v11 = xl1.y + xr1.y + ee11;
        v00 = v00 > 0.f ? v00 : 0.2f * v00;
        v01 = v01 > 0.f ? v01 : 0.2f * v01;
        v10 = v10 > 0.f ? v10 : 0.2f * v10;
        v11 = v11 > 0.f ? v11 : 0.2f * v11;
        float p00 = v00 * a0, p01 = v01 * a1;
        float p10 = v10 * a0, p11 = v11 * a1;
#pragma unroll
        for (int off = 32; off > 0; off >>= 1) {
            p00 += __shfl_xor(p00, off);
            p01 += __shfl_xor(p01, off);
            p10 += __shfl_xor(p10, off);
            p11 += __shfl_xor(p11, off);
        }
        if (lane == 0) {
            float ev0 = __expf(p00), ev1 = __expf(p01);
            evout[e0] = make_float2(ev0, ev1);
            atomicAdd(&denom[d0 * 2 + 0], ev0);
            atomicAdd(&denom[d0 * 2 + 1], ev1);
        }
        if (lane == 1) {
            float ev0 = __expf(p10), ev1 = __expf(p11);
            evout[e1] = make_float2(ev0, ev1);
            atomicAdd(&denom[d1 * 2 + 0], ev0);
            atomicAdd(&denom[d1 * 2 + 1], ev1);
        }
    }
}

// K7: out[dst] += 0.5 * sum_h alpha_h * xl[src,h,:]  (2 edges/iter ILP)
__global__ __launch_bounds__(256) void k_scatter(
    const int* __restrict__ ei, const float2* __restrict__ ev,
    const float2* __restrict__ denom, const __half2* __restrict__ xl2,
    float* __restrict__ out) {
    const int lane = threadIdx.x & 63;
    const int wid = threadIdx.x >> 6;
    long w = (long)blockIdx.x * 4 + wid;
    long nw = (long)gridDim.x * 4;
    const long NP = NA / 2;
    for (long p = w; p < NP; p += nw) {
        const long e0 = 2 * p, e1 = 2 * p + 1;
        int s0, d0, s1, d1;
        if (e0 < NE) {
            s0 = ei[e0]; d0 = ei[NE + e0];
            s1 = ei[e1]; d1 = ei[NE + e1];
        } else {
            s0 = d0 = (int)(e0 - NE);
            s1 = d1 = (int)(e1 - NE);
        }
        float2 ev0 = ev[e0], ev1 = ev[e1];
        float2 dn0 = denom[d0], dn1 = denom[d1];
        float2 x0 = __half22float2(xl2[(long)s0 * 64 + lane]);
        float2 x1 = __half22float2(xl2[(long)s1 * 64 + lane]);
        float al00 = ev0.x / (dn0.x + 1e-16f);
        float al01 = ev0.y / (dn0.y + 1e-16f);
        float al10 = ev1.x / (dn1.x + 1e-16f);
        float al11 = ev1.y / (dn1.y + 1e-16f);
        atomicAdd(&out[(long)d0 * CC + lane], 0.5f * (al00 * x0.x + al01 * x0.y));
        atomicAdd(&out[(long)d1 * CC + lane], 0.5f * (al10 * x1.x + al11 * x1.y));
    }
}

extern "C" void kernel_launch(void* const* d_in, const int* in_sizes, int n_in,
                              void* d_out, int out_size, void* d_ws, size_t ws_size,
                              hipStream_t stream) {
    const float* x    = (const float*)d_in[0];
    const float* eatt = (const float*)d_in[1];
    const float* gw   = (const float*)d_in[2];
    const float* gb   = (const float*)d_in[3];
    const float* gms  = (const float*)d_in[4];
    const float* Wl   = (const float*)d_in[5];
    const float* bl   = (const float*)d_in[6];
    const float* Wr   = (const float*)d_in[7];
    const float* br   = (const float*)d_in[8];
    const float* We   = (const float*)d_in[9];
    const float* att  = (const float*)d_in[10];
    const float* bias = (const float*)d_in[11];
    const int*   ei   = (const int*)d_in[12];
    const int*   batch= (const int*)d_in[13];
    float* out = (float*)d_out;
    float* ws = (float*)d_ws;

    float* cnt  = ws + OFF_CNT;
    float* sumx = ws + OFF_SUM;
    float* sum2 = ws + OFF_SUM2;
    float* A    = ws + OFF_A;
    float* B    = ws + OFF_B;
    float* deg  = ws + OFF_DEG;
    float* la   = ws + OFF_LA;
    float* den  = ws + OFF_DEN;
    float* evb  = ws + OFF_LOG;
    __half* xl  = (__half*)(ws + OFF_XL);
    __half* xr  = (__half*)(ws + OFF_XR);

    hipLaunchKernelGGL(k_init, dim3(4096), dim3(256), 0, stream, ws, out, bias);
    hipLaunchKernelGGL(k_gn_sum, dim3((NN + 15) / 16), dim3(64), 0, stream,
                       x, batch, sumx, sum2, cnt);
    hipLaunchKernelGGL(k_gn_ab, dim3(16), dim3(256), 0, stream,
                       sumx, sum2, cnt, gw, gb, gms, A, B);
    hipLaunchKernelGGL(k_gemm, dim3(NN / 16), dim3(128), 0, stream,
                       x, batch, A, B, Wl, bl, Wr, br, xl, xr);
    hipLaunchKernelGGL(k_loopattr, dim3(8192), dim3(256), 0, stream, ei, eatt, deg, la);
    hipLaunchKernelGGL(k_logits, dim3(8192), dim3(256), 0, stream,
                       ei, eatt, We, att, deg, la,
                       (const __half2*)xl, (const __half2*)xr, (float2*)evb, den);
    hipLaunchKernelGGL(k_scatter, dim3(8192), dim3(256), 0, stream,
                       ei, (const float2*)evb, (const float2*)den,
                       (const __half2*)xl, out);
}